// Round 9
// baseline (175.793 us; speedup 1.0000x reference)
//
#include <hip/hip_runtime.h>

#define H 4096
#define W 4096
#define TH 4                   // output rows per block
#define NR (TH + 2)            // staged rows (vertical halo)
#define BX 256                 // threads per block (4 waves)
#define STRIPS 4               // 4096 cols / 1024-wide strip
#define GY (H / TH)            // 1024
#define NEDGE (STRIPS * GY)    // 4096 edge blocks
#define NKPB 16                // keypoint blocks (64 kp each) — launched FIRST
#define SIDEOFF (2 * NR * 1024)   // float index of side-halo buffer in smem

#define MASK_W 1.0f
#define KPT_W 0.5f

struct Prep { float dx0, dx1, dx2, dx3, s0, s1, s2, s3; };

__device__ __forceinline__ float fast_sqrt(float x) {
    return __builtin_amdgcn_sqrtf(x);   // raw v_sqrt_f32 (~1 ulp)
}

// Async global->LDS, 16B per lane, fire-and-forget (no VGPR dest, cannot be
// sunk by the scheduler). LDS dest is wave-uniform base; HW adds lane*16.
__device__ __forceinline__ void async_cp16(const float* g, float* l) {
    __builtin_amdgcn_global_load_lds(
        (const __attribute__((address_space(1))) void*)g,
        (__attribute__((address_space(3))) void*)l,
        16, 0, 0);
}

// Build horizontal Sobel prep for staged row sr of image m from LDS.
__device__ __forceinline__ Prep mkprep(const float* smem, int m, int sr, int t, bool rowok) {
    if (!rowok) { Prep z = {0.f,0.f,0.f,0.f,0.f,0.f,0.f,0.f}; return z; }
    int base = ((m * NR + sr) << 10);
    float4 v = *(const float4*)&smem[base + (t << 2)];
    float lf = (t == 0)      ? smem[SIDEOFF + (m*NR+sr)*2 + 0] : smem[base + (t << 2) - 1];
    float rf = (t == BX - 1) ? smem[SIDEOFF + (m*NR+sr)*2 + 1] : smem[base + (t << 2) + 4];
    Prep o;
    o.dx0 = v.y - lf;
    o.dx1 = v.z - v.x;
    o.dx2 = v.w - v.y;
    o.dx3 = rf  - v.z;
    o.s0 = __fmaf_rn(2.f, v.x, lf  + v.y);
    o.s1 = __fmaf_rn(2.f, v.y, v.x + v.z);
    o.s2 = __fmaf_rn(2.f, v.z, v.y + v.w);
    o.s3 = __fmaf_rn(2.f, v.w, v.z + rf);
    return o;
}

__device__ __forceinline__ float edge1(float dxA, float dxB, float dxC, float sA, float sC) {
    float ex = dxA + __fmaf_rn(2.f, dxB, dxC);
    float ey = sC - sA;
    return fast_sqrt(__fmaf_rn(ex, ex, ey * ey));
}

__global__ __launch_bounds__(BX) void fused_kernel(const float* __restrict__ pred,
                                                   const float* __restrict__ targ,
                                                   const float* __restrict__ kp,
                                                   float* __restrict__ ws) {
    __shared__ float smem[SIDEOFF + 2 * NR * 2];   // 48 KB tile + 96 B side halo
    int bid = blockIdx.x;

    if (bid >= NKPB) {
        // ======================= edge-loss tile =======================
        int ebid = bid - NKPB;
        int gx = ebid & (STRIPS - 1);
        int gy = ebid >> 2;               // log2(STRIPS)=2
        int c0 = gx << 10;                // strip start col
        int r0 = gy * TH;
        int t  = threadIdx.x;
        int w  = t >> 6, lane = t & 63;

        // ---- async stage: 48 x 1KB global->LDS, all airborne before barrier ----
        #pragma unroll
        for (int jj = 0; jj < 12; ++jj) {
            int j  = w * 12 + jj;         // 0..47, wave-uniform
            int m  = j / 24;              // image
            int rr = (j % 24) >> 2;       // staged row 0..5
            int q  = j & 3;               // column quarter (256 floats)
            int rg = r0 - 1 + rr;
            rg = rg < 0 ? 0 : (rg > H - 1 ? H - 1 : rg);   // clamp; OOB zeroed at consume
            const float* g = (m ? targ : pred) + (size_t)rg * W + c0 + (q << 8) + (lane << 2);
            float* l = &smem[((m * NR + rr) << 10) + (q << 8)];
            async_cp16(g, l);
        }

        // ---- side halo scalars (cols c0-1 and c0+1024) ----
        if (t == 0 || t == BX - 1) {
            bool right = (t == BX - 1);
            int col = right ? c0 + 1024 : c0 - 1;
            bool cok = (unsigned)col < (unsigned)W;
            #pragma unroll
            for (int m = 0; m < 2; ++m) {
                #pragma unroll
                for (int rr = 0; rr < NR; ++rr) {
                    int rg = r0 - 1 + rr;
                    bool ok = cok & ((unsigned)rg < (unsigned)H);
                    int rgc = rg < 0 ? 0 : (rg > H - 1 ? H - 1 : rg);
                    float v = ok ? (m ? targ : pred)[(size_t)rgc * W + col] : 0.f;
                    smem[SIDEOFF + (m * NR + rr) * 2 + (right ? 1 : 0)] = v;
                }
            }
        }
        __syncthreads();   // vmcnt(0)+lgkmcnt(0) drain: tile fully landed

        bool ok0 = (r0 > 0);          // sr=0 (row r0-1) validity — block-uniform
        bool ok5 = (r0 + TH < H);     // sr=5 (row r0+4)

        Prep pA = mkprep(smem, 0, 0, t, ok0);
        Prep tA = mkprep(smem, 1, 0, t, ok0);
        Prep pB = mkprep(smem, 0, 1, t, true);
        Prep tB = mkprep(smem, 1, 1, t, true);

        float acc = 0.f;
        #pragma unroll
        for (int i = 0; i < TH; ++i) {
            bool rok = (i + 2 < NR - 1) ? true : ok5;
            Prep pC = mkprep(smem, 0, i + 2, t, rok);
            Prep tC = mkprep(smem, 1, i + 2, t, rok);

            float pe, te, d;
            pe = edge1(pA.dx0, pB.dx0, pC.dx0, pA.s0, pC.s0);
            te = edge1(tA.dx0, tB.dx0, tC.dx0, tA.s0, tC.s0);
            d = pe - te; acc = __fmaf_rn(d, d, acc);
            pe = edge1(pA.dx1, pB.dx1, pC.dx1, pA.s1, pC.s1);
            te = edge1(tA.dx1, tB.dx1, tC.dx1, tA.s1, tC.s1);
            d = pe - te; acc = __fmaf_rn(d, d, acc);
            pe = edge1(pA.dx2, pB.dx2, pC.dx2, pA.s2, pC.s2);
            te = edge1(tA.dx2, tB.dx2, tC.dx2, tA.s2, tC.s2);
            d = pe - te; acc = __fmaf_rn(d, d, acc);
            pe = edge1(pA.dx3, pB.dx3, pC.dx3, pA.s3, pC.s3);
            te = edge1(tA.dx3, tB.dx3, tC.dx3, tA.s3, tC.s3);
            d = pe - te; acc = __fmaf_rn(d, d, acc);

            pA = pB; pB = pC;
            tA = tB; tB = tC;
        }

        // wave reduce (width 64)
        #pragma unroll
        for (int m = 32; m; m >>= 1) acc += __shfl_xor(acc, m);

        __shared__ float wsum[BX / 64];
        if ((t & 63) == 0) wsum[t >> 6] = acc;
        __syncthreads();
        if (t == 0) {
            float s = 0.f;
            #pragma unroll
            for (int i = 0; i < BX / 64; ++i) s += wsum[i];
            ws[ebid] = s;
        }
    } else {
        // ======================= keypoint block (launched first) =======================
        int t = threadIdx.x;
        if (t >= 64) return;
        int k = bid * 64 + t;              // keypoint index 0..1023

        float gx = kp[2 * k];
        float gy = kp[2 * k + 1];
        float x = (gx + 1.f) * (W * 0.5f) - 0.5f;
        float y = (gy + 1.f) * (H * 0.5f) - 0.5f;
        float fx0 = floorf(x), fy0 = floorf(y);
        int x0 = (int)fx0, y0 = (int)fy0;
        int x1 = x0 + 1, y1 = y0 + 1;
        float wx1 = x - fx0, wx0 = 1.f - wx1;
        float wy1 = y - fy0, wy0 = 1.f - wy1;

        // 6x6 pred_seg patch around (y0, x0), zero-padded
        float sg[6][6];
        #pragma unroll
        for (int i = 0; i < 6; ++i) {
            int rr = y0 - 2 + i;
            #pragma unroll
            for (int j = 0; j < 6; ++j) {
                int cc = x0 - 2 + j;
                bool ok = (rr >= 0) & (rr < H) & (cc >= 0) & (cc < W);
                sg[i][j] = ok ? pred[(size_t)rr * W + cc] : 0.f;
            }
        }

        // 4x4 pred_edge for rows y0-1..y0+2, cols x0-1..x0+2 (0 when OOB)
        float e[4][4];
        #pragma unroll
        for (int i = 0; i < 4; ++i) {
            int rr = y0 - 1 + i;
            #pragma unroll
            for (int j = 0; j < 4; ++j) {
                int cc = x0 - 1 + j;
                if (rr < 0 || rr >= H || cc < 0 || cc >= W) { e[i][j] = 0.f; continue; }
                float ex = (sg[i][j + 2] - sg[i][j])
                         + 2.f * (sg[i + 1][j + 2] - sg[i + 1][j])
                         + (sg[i + 2][j + 2] - sg[i + 2][j]);
                float ey = (sg[i + 2][j] + 2.f * sg[i + 2][j + 1] + sg[i + 2][j + 2])
                         - (sg[i][j] + 2.f * sg[i][j + 1] + sg[i][j + 2]);
                e[i][j] = fast_sqrt(__fmaf_rn(ex, ex, ey * ey));
            }
        }

        // 2x2 distance-map values (3x3 box over pred_edge)
        float dmap[2][2];
        #pragma unroll
        for (int a = 0; a < 2; ++a) {
            #pragma unroll
            for (int b = 0; b < 2; ++b) {
                float s = 0.f;
                #pragma unroll
                for (int i = 0; i < 3; ++i)
                    #pragma unroll
                    for (int j = 0; j < 3; ++j) s += e[a + i][b + j];
                dmap[a][b] = s;
            }
        }

        bool vx0 = (x0 >= 0) & (x0 < W), vx1 = (x1 >= 0) & (x1 < W);
        bool vy0 = (y0 >= 0) & (y0 < H), vy1 = (y1 >= 0) & (y1 < H);
        float v00 = (vx0 & vy0) ? dmap[0][0] : 0.f;
        float v01 = (vx1 & vy0) ? dmap[0][1] : 0.f;
        float v10 = (vx0 & vy1) ? dmap[1][0] : 0.f;
        float v11 = (vx1 & vy1) ? dmap[1][1] : 0.f;
        float kd = wx0 * wy0 * v00 + wx1 * wy0 * v01
                 + wx0 * wy1 * v10 + wx1 * wy1 * v11;

        // wave reduce 64 kd values
        #pragma unroll
        for (int m = 32; m; m >>= 1) kd += __shfl_xor(kd, m);
        if (t == 0) ws[NEDGE + bid] = kd;
    }
}

__global__ __launch_bounds__(256) void final_kernel(const float* __restrict__ ws,
                                                    float* __restrict__ out) {
    int t = threadIdx.x;
    float es = 0.f;
    #pragma unroll
    for (int i = 0; i < NEDGE / 256; ++i) es += ws[t + i * 256];
    float ks = (t < NKPB) ? ws[NEDGE + t] : 0.f;

    #pragma unroll
    for (int m = 32; m; m >>= 1) {
        es += __shfl_xor(es, m);
        ks += __shfl_xor(ks, m);
    }
    __shared__ float res[4], rks[4];
    int wid = t >> 6;
    if ((t & 63) == 0) { res[wid] = es; rks[wid] = ks; }
    __syncthreads();
    if (t == 0) {
        float e2 = res[0] + res[1] + res[2] + res[3];
        float k2 = rks[0] + rks[1] + rks[2] + rks[3];
        float edge_loss = e2 * (1.f / ((float)H * (float)W));
        float constraint_loss = k2 * (1.f / 1024.f);
        out[0] = MASK_W * edge_loss + KPT_W * constraint_loss;
    }
}

extern "C" void kernel_launch(void* const* d_in, const int* in_sizes, int n_in,
                              void* d_out, int out_size, void* d_ws, size_t ws_size,
                              hipStream_t stream) {
    const float* kp   = (const float*)d_in[0];
    const float* pred = (const float*)d_in[2];
    const float* targ = (const float*)d_in[3];
    float* out = (float*)d_out;
    float* ws  = (float*)d_ws;

    fused_kernel<<<NEDGE + NKPB, BX, 0, stream>>>(pred, targ, kp, ws);
    final_kernel<<<1, 256, 0, stream>>>(ws, out);
}